// Round 16
// baseline (237.596 us; speedup 1.0000x reference)
//
#include <hip/hip_runtime.h>
#include <stdint.h>

typedef int v4i __attribute__((ext_vector_type(4)));
typedef int v2i __attribute__((ext_vector_type(2)));
typedef float float4_t __attribute__((ext_vector_type(4)));

#define K_DIM 1024
#define N_DIM 1024
#define BM 128
#define BN 128

// NT cache-policy (CPol) bit for gfx940+/gfx950 vmem aux field: SC0=1, NT=2,
// SC1=16. NT loads don't allocate in L2 -> L2 stays free for C-store
// write-combining; reads are served/retained by the 256MB L3.
__device__ __forceinline__ void gload16nt(const void* g, void* l) {
  __builtin_amdgcn_global_load_lds(
      (const __attribute__((address_space(1))) unsigned int*)g,
      (__attribute__((address_space(3))) unsigned int*)l, 16, 0, 2);
}
__device__ __forceinline__ void gload16(const void* g, void* l) {
  __builtin_amdgcn_global_load_lds(
      (const __attribute__((address_space(1))) unsigned int*)g,
      (__attribute__((address_space(3))) unsigned int*)l, 16, 0, 0);
}

#define MFMA_I8 __builtin_amdgcn_mfma_i32_16x16x64_i8

// LDS-only barrier (orders DS without draining the vmem store queue).
#define BAR_LDS()                                             \
  do {                                                        \
    asm volatile("s_waitcnt lgkmcnt(0)" ::: "memory");        \
    __builtin_amdgcn_s_barrier();                             \
  } while (0)

// ---------------------------------------------------------------------------
// Kernel 1: per-token FWHT + 4-bit quant, output PACKED u4. (unchanged R15)
// ---------------------------------------------------------------------------
__global__ __launch_bounds__(256) void fwht_quant_kernel(
    const float* __restrict__ x, int8_t* __restrict__ qxp,
    float* __restrict__ ascale, int M) {
  const int lane = threadIdx.x & 63;
  const int wid = threadIdx.x >> 6;
  const long token = (long)blockIdx.x * 4 + wid;
  if (token >= M) return;
  const float4_t* xr4 = (const float4_t*)(x + token * K_DIM);

  float v[16];
#pragma unroll
  for (int i = 0; i < 4; ++i) {
    float4_t f = xr4[lane * 4 + i];
#pragma unroll
    for (int c = 0; c < 4; ++c) v[i * 4 + c] = f[c];
  }
#pragma unroll
  for (int s = 1; s <= 8; s <<= 1) {
#pragma unroll
    for (int r = 0; r < 16; ++r)
      if ((r & s) == 0) {
        float a0 = v[r], b0 = v[r | s];
        v[r] = a0 + b0;
        v[r | s] = a0 - b0;
      }
  }
#pragma unroll
  for (int m = 1; m <= 32; m <<= 1) {
    const float sg = (lane & m) ? -1.0f : 1.0f;
#pragma unroll
    for (int r = 0; r < 16; ++r) {
      float p = __shfl_xor(v[r], m, 64);
      v[r] = fmaf(sg, v[r], p);
    }
  }
  float mx = 0.f;
#pragma unroll
  for (int r = 0; r < 16; ++r) mx = fmaxf(mx, fabsf(v[r]));
#pragma unroll
  for (int m = 32; m >= 1; m >>= 1) mx = fmaxf(mx, __shfl_xor(mx, m, 64));
  const float scale = fmaxf(mx * 0.03125f, 1e-5f) * (1.0f / 7.0f);
  if (lane == 0) ascale[token] = scale;
  const float inv = 0.03125f / scale;

  int u[16];
#pragma unroll
  for (int r = 0; r < 16; ++r) {
    float q = rintf(v[r] * inv);
    q = fminf(7.f, fmaxf(-8.f, q));
    u[r] = (int)q + 8;  // 0..15
  }
  v2i pk;
  int dw0 = 0, dw1 = 0;
#pragma unroll
  for (int j = 0; j < 4; ++j) {
    dw0 |= ((u[j] | (u[j + 8] << 4)) & 0xff) << (8 * j);
    dw1 |= ((u[j + 4] | (u[j + 12] << 4)) & 0xff) << (8 * j);
  }
  pk[0] = dw0;
  pk[1] = dw1;
  *(v2i*)(qxp + token * 512 + lane * 8) = pk;
}

// ---------------------------------------------------------------------------
// Kernel 2: ternary weight quant + per-row ternary SUM. (unchanged R15)
// ---------------------------------------------------------------------------
__global__ __launch_bounds__(256) void wquant_kernel(
    const float* __restrict__ w, int8_t* __restrict__ qw,
    float* __restrict__ wscale, int* __restrict__ tsum) {
  const int lane = threadIdx.x & 63;
  const int wid = threadIdx.x >> 6;
  const int row = blockIdx.x * 4 + wid;
  const float* wr = w + (long)row * K_DIM;

  float v[16];
  float s = 0.f;
  const float4_t* wr4 = (const float4_t*)wr;
#pragma unroll
  for (int rr = 0; rr < 4; ++rr) {
    float4_t f = wr4[rr * 64 + lane];
#pragma unroll
    for (int c = 0; c < 4; ++c) {
      v[rr * 4 + c] = f[c];
      s += fabsf(f[c]);
    }
  }
#pragma unroll
  for (int m = 32; m >= 1; m >>= 1) s += __shfl_xor(s, m, 64);
  const float scale = fmaxf(s * (1.0f / 1024.0f), 1e-5f);
  if (lane == 0) wscale[row] = scale;

  int8_t* qr = qw + (long)row * K_DIM;
  int tloc = 0;
#pragma unroll
  for (int rr = 0; rr < 4; ++rr) {
    int packed = 0;
#pragma unroll
    for (int c = 0; c < 4; ++c) {
      float n = v[rr * 4 + c] / scale;
      int tv = (n > 0.5f) ? 1 : ((n < -0.5f) ? -1 : 0);
      tloc += tv;
      packed |= (tv & 0xff) << (8 * c);
    }
    *(int*)(qr + rr * 256 + lane * 4) = packed;
  }
#pragma unroll
  for (int m = 32; m >= 1; m >>= 1) tloc += __shfl_xor(tloc, m, 64);
  if (lane == 0) tsum[row] = tloc;
}

// ---------------------------------------------------------------------------
// Kernel 3: int8 GEMM = R15 structure, ONE variable: inverted cache policy.
//  - A/B staging via gload_lds with NT aux (no L2 allocate; L3 serves reuse)
//  - C-stores PLAIN full-line float4 (write-combine in the now-clean L2 at
//    fill-like BW, drain async) instead of nt (measured cap ~2.5 TB/s,
//    which equals the whole GEMM duration -> the limiter).
// Kept: u4-packed A (+tsum epilogue correction), 2-phase dbuf K-loop,
// T1 XCD swizzle, chunk-XOR LDS, LDS-transpose epilogue (tr stride 132),
// LDS-only epilogue barriers. 48KB LDS -> 3 blocks/CU.
// ---------------------------------------------------------------------------
__global__ __launch_bounds__(256) void gemm_i8_kernel(
    const int8_t* __restrict__ Aq, const int8_t* __restrict__ B,
    const float* __restrict__ asc, const float* __restrict__ wsc,
    const int* __restrict__ tsum, float* __restrict__ C, int M) {
  __shared__ __align__(16) int8_t smem[49152];
  // layout: A0 [0,8K) A1 [8K,16K) B0 [16K,32K) B1 [32K,48K); tr aliases base
  float* tr = (float*)smem;  // epilogue: 64 rows x 132 f32 = 33792 B

  const int t = threadIdx.x;
  const int lane = t & 63;
  const int wm = (t >> 6) >> 1;
  const int wn = (t >> 6) & 1;
  const int rl = lane & 15;
  const int kb = lane >> 4;

  // T1: XCD swizzle. grid=4096 (%8==0): bm chunk per XCD, bn fastest.
  const int swz = ((int)blockIdx.x & 7) * 512 + ((int)blockIdx.x >> 3);
  const long bm = swz >> 3;  // 0..511
  const int bn = swz & 7;    // 0..7

  // A staging (u4-packed rows of 512B): granule t covers row t>>2, phys s16
  // t&3; content(ps) = logical ps ^ ((row>>1)&3) -> inverse on global src.
  const int arowS = t >> 2;
  const int apsS = (t & 3) ^ ((arowS >> 1) & 3);
  const int8_t* gA = Aq + (bm * BM + arowS) * 512L + apsS * 16;
  // B staging: 16B chunks, XOR (row&7).
  const int chunkoff = (((t & 7) ^ ((t >> 3) & 7)) << 4);
  const int8_t* gB = B + ((long)bn * BN + (t >> 3)) * K_DIM + chunkoff;

  // A frag addresses: row=(wm*64+i*16+rl), slot8=ks2*4+kb ->
  // s16=slot8>>1, half=kb&1; ps16 = s16 ^ ((rl>>1)&3).
  const int fA = (rl >> 1) & 3;
  const int aBase = (wm * 64 + rl) * 64 + (kb & 1) * 8;
  const int psA0 = ((kb >> 1) ^ fA) * 16;        // ks2=0
  const int psA1 = ((2 + (kb >> 1)) ^ fA) * 16;  // ks2=1
  const int sw0 = ((kb ^ (rl & 7)) << 4);
  const int sw1 = (((4 + kb) ^ (rl & 7)) << 4);
  const int brow = (wn * 64 + rl) * 128;

  v4i acc[4][4] = {};

#define STAGE(p, kt_)                                                     \
  gload16nt(gA + (kt_) * 64, smem + (p)*8192 + t * 16);                   \
  gload16nt(gA + 64 * 512 + (kt_) * 64, smem + (p)*8192 + 4096 + t * 16); \
  gload16nt(gB + (kt_) * 128, smem + 16384 + (p)*16384 + t * 16);         \
  gload16nt(gB + (kt_) * 128 + 32 * K_DIM,                                \
            smem + 16384 + (p)*16384 + 4096 + t * 16);                    \
  gload16nt(gB + (kt_) * 128 + 64 * K_DIM,                                \
            smem + 16384 + (p)*16384 + 8192 + t * 16);                    \
  gload16nt(gB + (kt_) * 128 + 96 * K_DIM,                                \
            smem + 16384 + (p)*16384 + 12288 + t * 16);

  STAGE(0, 0);
  __syncthreads();

#pragma unroll
  for (int kt = 0; kt < 8; ++kt) {
    const int p = kt & 1;
    if (kt < 7) {
      STAGE(p ^ 1, kt + 1);  // prefetch next tile under this compute
    }
    const int8_t* Al = smem + p * 8192;
    const int8_t* Bl = smem + 16384 + p * 16384;
#pragma unroll
    for (int ks2 = 0; ks2 < 2; ++ks2) {
      const int psA = ks2 ? psA1 : psA0;
      const int sw = ks2 ? sw1 : sw0;
      v4i a[4], b[4];
#pragma unroll
      for (int i = 0; i < 4; ++i) {
        v2i d = *(const v2i*)(Al + aBase + i * 1024 + psA);
        const unsigned u0 = (unsigned)d[0], u1 = (unsigned)d[1];
        a[i][0] = (int)(u0 & 0x0F0F0F0Fu);
        a[i][1] = (int)(u1 & 0x0F0F0F0Fu);
        a[i][2] = (int)((u0 >> 4) & 0x0F0F0F0Fu);
        a[i][3] = (int)((u1 >> 4) & 0x0F0F0F0Fu);
      }
#pragma unroll
      for (int j = 0; j < 4; ++j)
        b[j] = *(const v4i*)(Bl + brow + j * 2048 + sw);
#pragma unroll
      for (int i = 0; i < 4; ++i)
#pragma unroll
        for (int j = 0; j < 4; ++j)
          acc[i][j] = MFMA_I8(a[i], b[j], acc[i][j], 0, 0, 0);
    }
    __syncthreads();  // next tile landed; this tile's reads retired
  }
#undef STAGE

  // ---- LDS-transpose epilogue, 2 chunks of 64 rows, tr stride 132 ----
  // val = (acc - 8*tsum[col]) * ascale[row] * wscale[col]
  const long rowg0 = bm * BM + wm * 64;
  const int colg0 = bn * BN + wn * 64;
#pragma unroll
  for (int c = 0; c < 2; ++c) {
    if (wm == c) {
#pragma unroll
      for (int i = 0; i < 4; ++i) {
        float as[4];
#pragma unroll
        for (int r = 0; r < 4; ++r) as[r] = asc[rowg0 + i * 16 + kb * 4 + r];
#pragma unroll
        for (int j = 0; j < 4; ++j) {
          const int col = colg0 + j * 16 + rl;
          const float ws = wsc[col];
          const int corr = tsum[col] << 3;
#pragma unroll
          for (int r = 0; r < 4; ++r)
            tr[(i * 16 + kb * 4 + r) * 132 + wn * 64 + j * 16 + rl] =
                (float)(acc[i][j][r] - corr) * as[r] * ws;
        }
      }
    }
    BAR_LDS();  // deposits visible; no vmem drain
    // 256 threads x 8 PLAIN float4 stores: 32 lanes cover 512B = 4 full lines
#pragma unroll
    for (int it = 0; it < 8; ++it) {
      const int idx = t + it * 256;   // 0..2047
      const int rl2 = idx >> 5;       // local row 0..63
      const int c4 = (idx & 31) * 4;  // col in floats
      *(float4_t*)(C + (bm * BM + c * 64 + rl2) * (long)N_DIM + bn * BN + c4) =
          *(const float4_t*)(tr + rl2 * 132 + c4);
    }
    if (c == 0) BAR_LDS();  // tr ds_reads retired before re-deposit
  }
}

// ---------------------------------------------------------------------------
extern "C" void kernel_launch(void* const* d_in, const int* in_sizes, int n_in,
                              void* d_out, int out_size, void* d_ws, size_t ws_size,
                              hipStream_t stream) {
  const float* x = (const float*)d_in[0];  // [8,8192,1024] f32
  const float* w = (const float*)d_in[1];  // [1024,1024] f32
  float* out = (float*)d_out;              // [8,8192,1024] f32
  const int M = in_sizes[0] / K_DIM;       // 65536

  // workspace: qxp (M*512 u4-packed) | qw (N*K i8) | ascale | wscale | tsum
  int8_t* qxp = (int8_t*)d_ws;
  int8_t* qw = qxp + (size_t)M * 512;
  float* ascale = (float*)(qw + (size_t)N_DIM * K_DIM);
  float* wscale = ascale + M;
  int* tsum = (int*)(wscale + N_DIM);

  fwht_quant_kernel<<<(M + 3) / 4, 256, 0, stream>>>(x, qxp, ascale, M);
  wquant_kernel<<<N_DIM / 4, 256, 0, stream>>>(w, qw, wscale, tsum);
  gemm_i8_kernel<<<(M / BM) * (N_DIM / BN), 256, 0, stream>>>(qxp, qw, ascale, wscale, tsum, out, M);
}

// Round 17
// 171.759 us; speedup vs baseline: 1.3833x; 1.3833x over previous
//
#include <hip/hip_runtime.h>
#include <stdint.h>

typedef int v4i __attribute__((ext_vector_type(4)));
typedef int v2i __attribute__((ext_vector_type(2)));
typedef float float4_t __attribute__((ext_vector_type(4)));

#define K_DIM 1024
#define N_DIM 1024
#define BM 128
#define BN 64

__device__ __forceinline__ void gload16(const void* g, void* l) {
  __builtin_amdgcn_global_load_lds(
      (const __attribute__((address_space(1))) unsigned int*)g,
      (__attribute__((address_space(3))) unsigned int*)l, 16, 0, 0);
}

#define MFMA_I8 __builtin_amdgcn_mfma_i32_16x16x64_i8

// LDS-only barrier (orders DS without draining the vmem/nt-store queue).
#define BAR_LDS()                                             \
  do {                                                        \
    asm volatile("s_waitcnt lgkmcnt(0)" ::: "memory");        \
    __builtin_amdgcn_s_barrier();                             \
  } while (0)

// ---------------------------------------------------------------------------
// Kernel 1: per-token FWHT + 4-bit quant, output PACKED u4. (R15 verbatim)
// ---------------------------------------------------------------------------
__global__ __launch_bounds__(256) void fwht_quant_kernel(
    const float* __restrict__ x, int8_t* __restrict__ qxp,
    float* __restrict__ ascale, int M) {
  const int lane = threadIdx.x & 63;
  const int wid = threadIdx.x >> 6;
  const long token = (long)blockIdx.x * 4 + wid;
  if (token >= M) return;
  const float4_t* xr4 = (const float4_t*)(x + token * K_DIM);

  float v[16];
#pragma unroll
  for (int i = 0; i < 4; ++i) {
    float4_t f = xr4[lane * 4 + i];
#pragma unroll
    for (int c = 0; c < 4; ++c) v[i * 4 + c] = f[c];
  }
#pragma unroll
  for (int s = 1; s <= 8; s <<= 1) {
#pragma unroll
    for (int r = 0; r < 16; ++r)
      if ((r & s) == 0) {
        float a0 = v[r], b0 = v[r | s];
        v[r] = a0 + b0;
        v[r | s] = a0 - b0;
      }
  }
#pragma unroll
  for (int m = 1; m <= 32; m <<= 1) {
    const float sg = (lane & m) ? -1.0f : 1.0f;
#pragma unroll
    for (int r = 0; r < 16; ++r) {
      float p = __shfl_xor(v[r], m, 64);
      v[r] = fmaf(sg, v[r], p);
    }
  }
  float mx = 0.f;
#pragma unroll
  for (int r = 0; r < 16; ++r) mx = fmaxf(mx, fabsf(v[r]));
#pragma unroll
  for (int m = 32; m >= 1; m >>= 1) mx = fmaxf(mx, __shfl_xor(mx, m, 64));
  const float scale = fmaxf(mx * 0.03125f, 1e-5f) * (1.0f / 7.0f);
  if (lane == 0) ascale[token] = scale;
  const float inv = 0.03125f / scale;

  int u[16];
#pragma unroll
  for (int r = 0; r < 16; ++r) {
    float q = rintf(v[r] * inv);
    q = fminf(7.f, fmaxf(-8.f, q));
    u[r] = (int)q + 8;  // 0..15
  }
  v2i pk;
  int dw0 = 0, dw1 = 0;
#pragma unroll
  for (int j = 0; j < 4; ++j) {
    dw0 |= ((u[j] | (u[j + 8] << 4)) & 0xff) << (8 * j);
    dw1 |= ((u[j + 4] | (u[j + 12] << 4)) & 0xff) << (8 * j);
  }
  pk[0] = dw0;
  pk[1] = dw1;
  *(v2i*)(qxp + token * 512 + lane * 8) = pk;
}

// ---------------------------------------------------------------------------
// Kernel 2: ternary weight quant + per-row ternary SUM. (R15 verbatim)
// ---------------------------------------------------------------------------
__global__ __launch_bounds__(256) void wquant_kernel(
    const float* __restrict__ w, int8_t* __restrict__ qw,
    float* __restrict__ wscale, int* __restrict__ tsum) {
  const int lane = threadIdx.x & 63;
  const int wid = threadIdx.x >> 6;
  const int row = blockIdx.x * 4 + wid;
  const float* wr = w + (long)row * K_DIM;

  float v[16];
  float s = 0.f;
  const float4_t* wr4 = (const float4_t*)wr;
#pragma unroll
  for (int rr = 0; rr < 4; ++rr) {
    float4_t f = wr4[rr * 64 + lane];
#pragma unroll
    for (int c = 0; c < 4; ++c) {
      v[rr * 4 + c] = f[c];
      s += fabsf(f[c]);
    }
  }
#pragma unroll
  for (int m = 32; m >= 1; m >>= 1) s += __shfl_xor(s, m, 64);
  const float scale = fmaxf(s * (1.0f / 1024.0f), 1e-5f);
  if (lane == 0) wscale[row] = scale;

  int8_t* qr = qw + (long)row * K_DIM;
  int tloc = 0;
#pragma unroll
  for (int rr = 0; rr < 4; ++rr) {
    int packed = 0;
#pragma unroll
    for (int c = 0; c < 4; ++c) {
      float n = v[rr * 4 + c] / scale;
      int tv = (n > 0.5f) ? 1 : ((n < -0.5f) ? -1 : 0);
      tloc += tv;
      packed |= (tv & 0xff) << (8 * c);
    }
    *(int*)(qr + rr * 256 + lane * 4) = packed;
  }
#pragma unroll
  for (int m = 32; m >= 1; m >>= 1) tloc += __shfl_xor(tloc, m, 64);
  if (lane == 0) tsum[row] = tloc;
}

// ---------------------------------------------------------------------------
// Kernel 3: int8 GEMM = R15 pipeline at 128x64 tile for OCCUPANCY.
// R16 PMC: MfmaUtil 17 / VALUBusy 20 / Occupancy 20% -- all low =
// latency-bound; LDS (48KB -> 3 blk/CU) was the binder. Now:
// LDS = A-dbuf 2x8KB (u4) + B-dbuf 2x8KB = 32KB exactly -> 5 blocks/CU
// (20 waves). Kept verbatim: nt full-line stores, LDS-only barriers,
// chunk-XOR both operands, u4 A path + tsum correction, 2-phase dbuf.
// T1: grid 8192; each bm gets 16 bn-blocks on one XCD (A fetched once/XCD).
// Epilogue tr = 2 chunks 64x64 f32 (16KB, aliases A region exactly).
// ---------------------------------------------------------------------------
__global__ __launch_bounds__(256, 5) void gemm_i8_kernel(
    const int8_t* __restrict__ Aq, const int8_t* __restrict__ B,
    const float* __restrict__ asc, const float* __restrict__ wsc,
    const int* __restrict__ tsum, float* __restrict__ C, int M) {
  __shared__ __align__(16) int8_t smem[32768];
  // A0 [0,8K) A1 [8K,16K) B0 [16K,24K) B1 [24K,32K); tr aliases [0,16K)
  float* tr = (float*)smem;  // 64 rows x 64 f32 = 16384 B per chunk

  const int t = threadIdx.x;
  const int lane = t & 63;
  const int wm = (t >> 6) >> 1;  // 0..1 (64-row half)
  const int wn = (t >> 6) & 1;   // 0..1 (32-col half)
  const int rl = lane & 15;
  const int kb = lane >> 4;

  // T1: XCD swizzle. grid=8192 (%8==0). XCD x: swz [x*1024, x*1024+1023] ->
  // bm chunk of 64 with bn (0..15) fastest: A-tile fetched once per XCD.
  const int swz = ((int)blockIdx.x & 7) * 1024 + ((int)blockIdx.x >> 3);
  const long bm = swz >> 4;  // 0..511
  const int bn = swz & 15;   // 0..15

  // A staging (u4 rows of 512B; kt-slice = 64B): granule t covers row t>>2,
  // phys s16 t&3; content(ps)=logical ps^((row>>1)&3) -> inverse on src.
  const int arowS = t >> 2;
  const int apsS = (t & 3) ^ ((arowS >> 1) & 3);
  const int8_t* gA = Aq + (bm * BM + arowS) * 512L + apsS * 16;
  // B staging (i8 rows of 1024B; kt-slice = 128B): row t>>3, chunk t&7,
  // XOR (row&7).
  const int chunkoff = (((t & 7) ^ ((t >> 3) & 7)) << 4);
  const int8_t* gB = B + ((long)bn * BN + (t >> 3)) * K_DIM + chunkoff;

  // A frag addresses (R15-verified u4 path): row=(wm*64+i*16+rl),
  // slot8=ks2*4+kb -> s16=slot8>>1, half=kb&1; ps16 = s16 ^ ((rl>>1)&3).
  const int fA = (rl >> 1) & 3;
  const int aBase = (wm * 64 + rl) * 64 + (kb & 1) * 8;
  const int psA0 = ((kb >> 1) ^ fA) * 16;        // ks2=0
  const int psA1 = ((2 + (kb >> 1)) ^ fA) * 16;  // ks2=1
  // B frag offsets.
  const int sw0 = ((kb ^ (rl & 7)) << 4);
  const int sw1 = (((4 + kb) ^ (rl & 7)) << 4);
  const int brow = (wn * 32 + rl) * 128;

  v4i acc[4][2] = {};

#define STAGE(p, kt_)                                                      \
  gload16(gA + (kt_) * 64, smem + (p)*8192 + t * 16);                      \
  gload16(gA + 64 * 512 + (kt_) * 64, smem + (p)*8192 + 4096 + t * 16);    \
  gload16(gB + (kt_) * 128, smem + 16384 + (p)*8192 + t * 16);             \
  gload16(gB + (kt_) * 128 + 32 * K_DIM,                                   \
          smem + 16384 + (p)*8192 + 4096 + t * 16);

  STAGE(0, 0);
  __syncthreads();

#pragma unroll
  for (int kt = 0; kt < 8; ++kt) {
    const int p = kt & 1;
    if (kt < 7) {
      STAGE(p ^ 1, kt + 1);  // prefetch next tile under this compute
    }
    const int8_t* Al = smem + p * 8192;
    const int8_t* Bl = smem + 16384 + p * 8192;
#pragma unroll
    for (int ks2 = 0; ks2 < 2; ++ks2) {
      const int psA = ks2 ? psA1 : psA0;
      const int sw = ks2 ? sw1 : sw0;
      v4i a[4], b[2];
#pragma unroll
      for (int i = 0; i < 4; ++i) {
        v2i d = *(const v2i*)(Al + aBase + i * 1024 + psA);
        const unsigned u0 = (unsigned)d[0], u1 = (unsigned)d[1];
        a[i][0] = (int)(u0 & 0x0F0F0F0Fu);
        a[i][1] = (int)(u1 & 0x0F0F0F0Fu);
        a[i][2] = (int)((u0 >> 4) & 0x0F0F0F0Fu);
        a[i][3] = (int)((u1 >> 4) & 0x0F0F0F0Fu);
      }
#pragma unroll
      for (int j = 0; j < 2; ++j)
        b[j] = *(const v4i*)(Bl + brow + j * 2048 + sw);
#pragma unroll
      for (int i = 0; i < 4; ++i)
#pragma unroll
        for (int j = 0; j < 2; ++j)
          acc[i][j] = MFMA_I8(a[i], b[j], acc[i][j], 0, 0, 0);
    }
    __syncthreads();  // next tile landed; this tile's reads retired
  }
#undef STAGE

  // ---- LDS-transpose epilogue: 2 chunks of 64 rows x 64 cols, stride 64 ----
  // val = (acc - 8*tsum[col]) * ascale[row] * wscale[col]
  const long rowg0 = bm * BM + wm * 64;
  const int colg0 = bn * BN + wn * 32;
#pragma unroll
  for (int c = 0; c < 2; ++c) {
    if (wm == c) {
#pragma unroll
      for (int i = 0; i < 4; ++i) {
        float as[4];
#pragma unroll
        for (int r = 0; r < 4; ++r) as[r] = asc[rowg0 + i * 16 + kb * 4 + r];
#pragma unroll
        for (int j = 0; j < 2; ++j) {
          const int col = colg0 + j * 16 + rl;
          const float ws = wsc[col];
          const int corr = tsum[col] << 3;
#pragma unroll
          for (int r = 0; r < 4; ++r)
            tr[(i * 16 + kb * 4 + r) * 64 + wn * 32 + j * 16 + rl] =
                (float)(acc[i][j][r] - corr) * as[r] * ws;
        }
      }
    }
    BAR_LDS();  // deposits visible; no vmem drain
    // 256 thr x 4 float4 nt stores: 16 lanes cover one 256B row segment
#pragma unroll
    for (int it = 0; it < 4; ++it) {
      const int idx = t + it * 256;   // 0..1023
      const int row = idx >> 4;       // local row 0..63
      const int c4 = (idx & 15) * 4;  // col in floats 0..60
      const float4_t val = *(const float4_t*)(tr + row * 64 + c4);
      __builtin_nontemporal_store(
          val, (float4_t*)(C + (bm * BM + c * 64 + row) * (long)N_DIM + bn * BN + c4));
    }
    if (c == 0) BAR_LDS();  // tr ds_reads retired before re-deposit
  }
}

// ---------------------------------------------------------------------------
extern "C" void kernel_launch(void* const* d_in, const int* in_sizes, int n_in,
                              void* d_out, int out_size, void* d_ws, size_t ws_size,
                              hipStream_t stream) {
  const float* x = (const float*)d_in[0];  // [8,8192,1024] f32
  const float* w = (const float*)d_in[1];  // [1024,1024] f32
  float* out = (float*)d_out;              // [8,8192,1024] f32
  const int M = in_sizes[0] / K_DIM;       // 65536

  // workspace: qxp (M*512 u4-packed) | qw (N*K i8) | ascale | wscale | tsum
  int8_t* qxp = (int8_t*)d_ws;
  int8_t* qw = qxp + (size_t)M * 512;
  float* ascale = (float*)(qw + (size_t)N_DIM * K_DIM);
  float* wscale = ascale + M;
  int* tsum = (int*)(wscale + N_DIM);

  fwht_quant_kernel<<<(M + 3) / 4, 256, 0, stream>>>(x, qxp, ascale, M);
  wquant_kernel<<<N_DIM / 4, 256, 0, stream>>>(w, qw, wscale, tsum);
  gemm_i8_kernel<<<(M / BM) * (N_DIM / BN), 256, 0, stream>>>(qxp, qw, ascale, wscale, tsum, out, M);
}

// Round 18
// 162.304 us; speedup vs baseline: 1.4639x; 1.0583x over previous
//
#include <hip/hip_runtime.h>
#include <stdint.h>

typedef int v4i __attribute__((ext_vector_type(4)));
typedef int v2i __attribute__((ext_vector_type(2)));
typedef float float4_t __attribute__((ext_vector_type(4)));

#define K_DIM 1024
#define N_DIM 1024
#define BM 128
#define BN 128

__device__ __forceinline__ void gload16(const void* g, void* l) {
  __builtin_amdgcn_global_load_lds(
      (const __attribute__((address_space(1))) unsigned int*)g,
      (__attribute__((address_space(3))) unsigned int*)l, 16, 0, 0);
}

#define MFMA_I8 __builtin_amdgcn_mfma_i32_16x16x64_i8

// LDS-only barrier (orders DS without draining the vmem/nt-store queue).
#define BAR_LDS()                                             \
  do {                                                        \
    asm volatile("s_waitcnt lgkmcnt(0)" ::: "memory");        \
    __builtin_amdgcn_s_barrier();                             \
  } while (0)

// ---------------------------------------------------------------------------
// Kernel 1 (MERGED): blocks [0, M/4): per-token FWHT + 4-bit quant, packed
// u4 output (R15 verbatim). Blocks [M/4, M/4+256): per-row ternary weight
// quant + tsum (R15 verbatim). One launch -> wquant hides under FWHT tail.
// ---------------------------------------------------------------------------
__global__ __launch_bounds__(256) void prep_kernel(
    const float* __restrict__ x, int8_t* __restrict__ qxp,
    float* __restrict__ ascale, const float* __restrict__ w,
    int8_t* __restrict__ qw, float* __restrict__ wscale,
    int* __restrict__ tsum, int M) {
  const int lane = threadIdx.x & 63;
  const int wid = threadIdx.x >> 6;
  const int nfw = M >> 2;  // FWHT blocks

  if ((int)blockIdx.x < nfw) {
    // ---------------- FWHT + activation quant (R15 verbatim) ----------------
    const long token = (long)blockIdx.x * 4 + wid;
    const float4_t* xr4 = (const float4_t*)(x + token * K_DIM);

    float v[16];
#pragma unroll
    for (int i = 0; i < 4; ++i) {
      float4_t f = xr4[lane * 4 + i];
#pragma unroll
      for (int c = 0; c < 4; ++c) v[i * 4 + c] = f[c];
    }
#pragma unroll
    for (int s = 1; s <= 8; s <<= 1) {
#pragma unroll
      for (int r = 0; r < 16; ++r)
        if ((r & s) == 0) {
          float a0 = v[r], b0 = v[r | s];
          v[r] = a0 + b0;
          v[r | s] = a0 - b0;
        }
    }
#pragma unroll
    for (int m = 1; m <= 32; m <<= 1) {
      const float sg = (lane & m) ? -1.0f : 1.0f;
#pragma unroll
      for (int r = 0; r < 16; ++r) {
        float p = __shfl_xor(v[r], m, 64);
        v[r] = fmaf(sg, v[r], p);
      }
    }
    float mx = 0.f;
#pragma unroll
    for (int r = 0; r < 16; ++r) mx = fmaxf(mx, fabsf(v[r]));
#pragma unroll
    for (int m = 32; m >= 1; m >>= 1) mx = fmaxf(mx, __shfl_xor(mx, m, 64));
    const float scale = fmaxf(mx * 0.03125f, 1e-5f) * (1.0f / 7.0f);
    if (lane == 0) ascale[token] = scale;
    const float inv = 0.03125f / scale;

    int u[16];
#pragma unroll
    for (int r = 0; r < 16; ++r) {
      float q = rintf(v[r] * inv);
      q = fminf(7.f, fmaxf(-8.f, q));
      u[r] = (int)q + 8;  // 0..15
    }
    v2i pk;
    int dw0 = 0, dw1 = 0;
#pragma unroll
    for (int j = 0; j < 4; ++j) {
      dw0 |= ((u[j] | (u[j + 8] << 4)) & 0xff) << (8 * j);
      dw1 |= ((u[j + 4] | (u[j + 12] << 4)) & 0xff) << (8 * j);
    }
    pk[0] = dw0;
    pk[1] = dw1;
    *(v2i*)(qxp + token * 512 + lane * 8) = pk;
  } else {
    // ---------------- weight ternary quant + tsum (R15 verbatim) -----------
    const int row = ((int)blockIdx.x - nfw) * 4 + wid;
    const float* wr = w + (long)row * K_DIM;

    float v[16];
    float s = 0.f;
    const float4_t* wr4 = (const float4_t*)wr;
#pragma unroll
    for (int rr = 0; rr < 4; ++rr) {
      float4_t f = wr4[rr * 64 + lane];
#pragma unroll
      for (int c = 0; c < 4; ++c) {
        v[rr * 4 + c] = f[c];
        s += fabsf(f[c]);
      }
    }
#pragma unroll
    for (int m = 32; m >= 1; m >>= 1) s += __shfl_xor(s, m, 64);
    const float scale = fmaxf(s * (1.0f / 1024.0f), 1e-5f);
    if (lane == 0) wscale[row] = scale;

    int8_t* qr = qw + (long)row * K_DIM;
    int tloc = 0;
#pragma unroll
    for (int rr = 0; rr < 4; ++rr) {
      int packed = 0;
#pragma unroll
      for (int c = 0; c < 4; ++c) {
        float n = v[rr * 4 + c] / scale;
        int tv = (n > 0.5f) ? 1 : ((n < -0.5f) ? -1 : 0);
        tloc += tv;
        packed |= (tv & 0xff) << (8 * c);
      }
      *(int*)(qr + rr * 256 + lane * 4) = packed;
    }
#pragma unroll
    for (int m = 32; m >= 1; m >>= 1) tloc += __shfl_xor(tloc, m, 64);
    if (lane == 0) tsum[row] = tloc;
  }
}

// ---------------------------------------------------------------------------
// Kernel 2: int8 GEMM — R15 VERBATIM (best measured: 164.4 total).
// u4-packed A (2x8KB dbuf) + i8 B (2x16KB dbuf), 2-phase prefetch K-loop,
// T1 XCD swizzle, chunk-XOR LDS both operands, u4 unpack -> i8 MFMA with
// tsum epilogue correction, LDS-transpose epilogue (tr stride 132) with
// full-line float4 nt stores and LDS-only barriers. 48KB LDS, 3 blocks/CU.
// ---------------------------------------------------------------------------
__global__ __launch_bounds__(256) void gemm_i8_kernel(
    const int8_t* __restrict__ Aq, const int8_t* __restrict__ B,
    const float* __restrict__ asc, const float* __restrict__ wsc,
    const int* __restrict__ tsum, float* __restrict__ C, int M) {
  __shared__ __align__(16) int8_t smem[49152];
  // layout: A0 [0,8K) A1 [8K,16K) B0 [16K,32K) B1 [32K,48K); tr aliases base
  float* tr = (float*)smem;  // epilogue: 64 rows x 132 f32 = 33792 B

  const int t = threadIdx.x;
  const int lane = t & 63;
  const int wm = (t >> 6) >> 1;
  const int wn = (t >> 6) & 1;
  const int rl = lane & 15;
  const int kb = lane >> 4;

  // T1: XCD swizzle. grid=4096 (%8==0): bm chunk per XCD, bn fastest.
  const int swz = ((int)blockIdx.x & 7) * 512 + ((int)blockIdx.x >> 3);
  const long bm = swz >> 3;  // 0..511
  const int bn = swz & 7;    // 0..7

  // A staging (u4-packed rows of 512B): granule t covers row t>>2, phys s16
  // t&3; content(ps) = logical ps ^ ((row>>1)&3) -> inverse on global src.
  const int arowS = t >> 2;
  const int apsS = (t & 3) ^ ((arowS >> 1) & 3);
  const int8_t* gA = Aq + (bm * BM + arowS) * 512L + apsS * 16;
  // B staging: 16B chunks, XOR (row&7).
  const int chunkoff = (((t & 7) ^ ((t >> 3) & 7)) << 4);
  const int8_t* gB = B + ((long)bn * BN + (t >> 3)) * K_DIM + chunkoff;

  // A frag addresses: row=(wm*64+i*16+rl), slot8=ks2*4+kb ->
  // s16=slot8>>1, half=kb&1; ps16 = s16 ^ ((rl>>1)&3).
  const int fA = (rl >> 1) & 3;
  const int aBase = (wm * 64 + rl) * 64 + (kb & 1) * 8;
  const int psA0 = ((kb >> 1) ^ fA) * 16;        // ks2=0
  const int psA1 = ((2 + (kb >> 1)) ^ fA) * 16;  // ks2=1
  const int sw0 = ((kb ^ (rl & 7)) << 4);
  const int sw1 = (((4 + kb) ^ (rl & 7)) << 4);
  const int brow = (wn * 64 + rl) * 128;

  v4i acc[4][4] = {};

#define STAGE(p, kt_)                                                   \
  gload16(gA + (kt_) * 64, smem + (p)*8192 + t * 16);                   \
  gload16(gA + 64 * 512 + (kt_) * 64, smem + (p)*8192 + 4096 + t * 16); \
  gload16(gB + (kt_) * 128, smem + 16384 + (p)*16384 + t * 16);         \
  gload16(gB + (kt_) * 128 + 32 * K_DIM,                                \
          smem + 16384 + (p)*16384 + 4096 + t * 16);                    \
  gload16(gB + (kt_) * 128 + 64 * K_DIM,                                \
          smem + 16384 + (p)*16384 + 8192 + t * 16);                    \
  gload16(gB + (kt_) * 128 + 96 * K_DIM,                                \
          smem + 16384 + (p)*16384 + 12288 + t * 16);

  STAGE(0, 0);
  __syncthreads();

#pragma unroll
  for (int kt = 0; kt < 8; ++kt) {
    const int p = kt & 1;
    if (kt < 7) {
      STAGE(p ^ 1, kt + 1);  // prefetch next tile under this compute
    }
    const int8_t* Al = smem + p * 8192;
    const int8_t* Bl = smem + 16384 + p * 16384;
#pragma unroll
    for (int ks2 = 0; ks2 < 2; ++ks2) {
      const int psA = ks2 ? psA1 : psA0;
      const int sw = ks2 ? sw1 : sw0;
      v4i a[4], b[4];
#pragma unroll
      for (int i = 0; i < 4; ++i) {
        v2i d = *(const v2i*)(Al + aBase + i * 1024 + psA);
        const unsigned u0 = (unsigned)d[0], u1 = (unsigned)d[1];
        a[i][0] = (int)(u0 & 0x0F0F0F0Fu);
        a[i][1] = (int)(u1 & 0x0F0F0F0Fu);
        a[i][2] = (int)((u0 >> 4) & 0x0F0F0F0Fu);
        a[i][3] = (int)((u1 >> 4) & 0x0F0F0F0Fu);
      }
#pragma unroll
      for (int j = 0; j < 4; ++j)
        b[j] = *(const v4i*)(Bl + brow + j * 2048 + sw);
#pragma unroll
      for (int i = 0; i < 4; ++i)
#pragma unroll
        for (int j = 0; j < 4; ++j)
          acc[i][j] = MFMA_I8(a[i], b[j], acc[i][j], 0, 0, 0);
    }
    __syncthreads();  // next tile landed; this tile's reads retired
  }
#undef STAGE

  // ---- LDS-transpose epilogue, 2 chunks of 64 rows, tr stride 132 ----
  // val = (acc - 8*tsum[col]) * ascale[row] * wscale[col]
  const long rowg0 = bm * BM + wm * 64;
  const int colg0 = bn * BN + wn * 64;
#pragma unroll
  for (int c = 0; c < 2; ++c) {
    if (wm == c) {
#pragma unroll
      for (int i = 0; i < 4; ++i) {
        float as[4];
#pragma unroll
        for (int r = 0; r < 4; ++r) as[r] = asc[rowg0 + i * 16 + kb * 4 + r];
#pragma unroll
        for (int j = 0; j < 4; ++j) {
          const int col = colg0 + j * 16 + rl;
          const float ws = wsc[col];
          const int corr = tsum[col] << 3;
#pragma unroll
          for (int r = 0; r < 4; ++r)
            tr[(i * 16 + kb * 4 + r) * 132 + wn * 64 + j * 16 + rl] =
                (float)(acc[i][j][r] - corr) * as[r] * ws;
        }
      }
    }
    BAR_LDS();  // deposits visible; no vmem drain
    // 256 threads x 8 float4 nt stores: 32 lanes cover 512B = 4 full lines
#pragma unroll
    for (int it = 0; it < 8; ++it) {
      const int idx = t + it * 256;   // 0..2047
      const int rl2 = idx >> 5;       // local row 0..63
      const int c4 = (idx & 31) * 4;  // col in floats
      const float4_t val = *(const float4_t*)(tr + rl2 * 132 + c4);
      __builtin_nontemporal_store(
          val, (float4_t*)(C + (bm * BM + c * 64 + rl2) * (long)N_DIM + bn * BN + c4));
    }
    if (c == 0) BAR_LDS();  // tr ds_reads retired before re-deposit
  }
}

// ---------------------------------------------------------------------------
extern "C" void kernel_launch(void* const* d_in, const int* in_sizes, int n_in,
                              void* d_out, int out_size, void* d_ws, size_t ws_size,
                              hipStream_t stream) {
  const float* x = (const float*)d_in[0];  // [8,8192,1024] f32
  const float* w = (const float*)d_in[1];  // [1024,1024] f32
  float* out = (float*)d_out;              // [8,8192,1024] f32
  const int M = in_sizes[0] / K_DIM;       // 65536

  // workspace: qxp (M*512 u4-packed) | qw (N*K i8) | ascale | wscale | tsum
  int8_t* qxp = (int8_t*)d_ws;
  int8_t* qw = qxp + (size_t)M * 512;
  float* ascale = (float*)(qw + (size_t)N_DIM * K_DIM);
  float* wscale = ascale + M;
  int* tsum = (int*)(wscale + N_DIM);

  prep_kernel<<<M / 4 + N_DIM / 4, 256, 0, stream>>>(x, qxp, ascale, w, qw,
                                                     wscale, tsum, M);
  gemm_i8_kernel<<<(M / BM) * (N_DIM / BN), 256, 0, stream>>>(
      qxp, qw, ascale, wscale, tsum, out, M);
}